// Round 7
// baseline (2017.551 us; speedup 1.0000x reference)
//
#include <hip/hip_runtime.h>
#include <hip/hip_fp16.h>

#define DN 256
#define KTOT 512
#define GBM 128
#define GBK 64
#define BKT_NODES 32
#define NPART 8
#define LDS_CAP 4096

typedef __attribute__((ext_vector_type(8))) short bf16x8;
typedef __attribute__((ext_vector_type(8))) unsigned short u16x8;
typedef __attribute__((ext_vector_type(4))) float f32x4;

__device__ __forceinline__ unsigned short f2b(float f) {
    unsigned u = __float_as_uint(f);
    u += 0x7FFF + ((u >> 16) & 1);   // round-to-nearest-even
    return (unsigned short)(u >> 16);
}
__device__ __forceinline__ float b2f(unsigned short b) {
    return __uint_as_float(((unsigned)b) << 16);
}

// ---- bucket binning ----------------------------------------------------
// key = (dst >> 5) * 8 + (blockIdx.x & 7). The partition term approximates
// XCD residency under round-robin dispatch (perf only); counts are exact
// because both passes use the identical blockIdx-derived key.

__global__ void k_bhist(const int* __restrict__ edst, int* __restrict__ hist, int E) {
    int e = blockIdx.x * 256 + threadIdx.x;
    if (e < E) atomicAdd(&hist[(edst[e] >> 5) * NPART + (blockIdx.x & 7)], 1);
}

__global__ void k_bscatter(const int* __restrict__ esrc, const int* __restrict__ edst,
                           const float* __restrict__ vals, int* __restrict__ cursor,
                           long long* __restrict__ mid, int E) {
    int e = blockIdx.x * 256 + threadIdx.x;
    if (e < E) {
        int d = edst[e];
        int pos = atomicAdd(&cursor[(d >> 5) * NPART + (blockIdx.x & 7)], 1);
        unsigned lo = (unsigned)esrc[e] | ((unsigned)(d & 31) << 20);  // src<2^20
        mid[pos] = (long long)lo | ((long long)(unsigned)__float_as_int(vals[e]) << 32);
    }
}

// ---- generic hierarchical exclusive scan (length L <= 128*1024) --------

__global__ void k_block_sums(const int* __restrict__ v, int* __restrict__ bsum, int L) {
    __shared__ int s[256];
    int t = threadIdx.x;
    int base = blockIdx.x * 1024 + t * 4;
    int sum = 0;
#pragma unroll
    for (int j = 0; j < 4; ++j) {
        int i = base + j;
        if (i < L) sum += v[i];
    }
    s[t] = sum;
    __syncthreads();
    for (int off = 128; off > 0; off >>= 1) {
        if (t < off) s[t] += s[t + off];
        __syncthreads();
    }
    if (t == 0) bsum[blockIdx.x] = s[0];
}

__global__ void k_scan_bsums(const int* __restrict__ bsum, int* __restrict__ boffs, int NB) {
    __shared__ int s[128];
    int t = threadIdx.x;
    int v = (t < NB) ? bsum[t] : 0;
    s[t] = v;
    __syncthreads();
    for (int off = 1; off < 128; off <<= 1) {
        int u = (t >= off) ? s[t - off] : 0;
        __syncthreads();
        s[t] += u;
        __syncthreads();
    }
    if (t < NB) boffs[t] = s[t] - v;
}

__global__ void k_scan_final(const int* __restrict__ v, const int* __restrict__ boffs,
                             int* __restrict__ offs, int* __restrict__ cursor,
                             int L, int E) {
    __shared__ int s[256];
    int t = threadIdx.x;
    int base = blockIdx.x * 1024 + t * 4;
    int d[4];
    int sum = 0;
#pragma unroll
    for (int j = 0; j < 4; ++j) {
        int i = base + j;
        d[j] = (i < L) ? v[i] : 0;
        sum += d[j];
    }
    s[t] = sum;
    __syncthreads();
    for (int off = 1; off < 256; off <<= 1) {
        int u = (t >= off) ? s[t - off] : 0;
        __syncthreads();
        s[t] += u;
        __syncthreads();
    }
    int p = boffs[blockIdx.x] + s[t] - sum;
#pragma unroll
    for (int j = 0; j < 4; ++j) {
        int i = base + j;
        if (i < L) {
            offs[i]   = p;
            cursor[i] = p;
            p += d[j];
        }
    }
    if (blockIdx.x == 0 && t == 0) offs[L] = E;
}

// ---- conversions -------------------------------------------------------

__global__ void k_cvt_x(const float* __restrict__ x, __half* __restrict__ xh, int total8) {
    int t = blockIdx.x * blockDim.x + threadIdx.x;
    if (t >= total8) return;
    const float4* p = (const float4*)(x + (size_t)t * 8);
    float4 a = p[0], b = p[1];
    __half h[8];
    h[0] = __float2half(a.x); h[1] = __float2half(a.y);
    h[2] = __float2half(a.z); h[3] = __float2half(a.w);
    h[4] = __float2half(b.x); h[5] = __float2half(b.y);
    h[6] = __float2half(b.z); h[7] = __float2half(b.w);
    *(u16x8*)(xh + (size_t)t * 8) = *(const u16x8*)h;
}

// Wcat[512][256] -> transposed split bf16: wt_hi/wt_lo layout [n][k]
__global__ void k_cvt_w(const float* __restrict__ wn, const float* __restrict__ wo,
                        unsigned short* __restrict__ wth, unsigned short* __restrict__ wtl) {
    int t = blockIdx.x * blockDim.x + threadIdx.x;  // t = k*256 + n
    int k = t >> 8;
    int n = t & 255;
    float v = (k < 256) ? wn[k * 256 + n] : wo[(k - 256) * 256 + n];
    unsigned short h = f2b(v);
    unsigned short l = f2b(v - b2f(h));
    wth[(size_t)n * KTOT + k] = h;
    wtl[(size_t)n * KTOT + k] = l;
}

// ---- fused bucket aggregation: agg = A @ x into out --------------------
// one block per 32-node bucket; wave w register-accumulates the 8 nodes
// with (dst_lo & 3) == w. No per-node sort, no LDS atomics.

template<int USE_F16>
__global__ __launch_bounds__(256) void k_agg_bkt(const __half* __restrict__ xh,
                                                 const float* __restrict__ xf,
                                                 const int* __restrict__ offs,
                                                 const long long* __restrict__ mid,
                                                 float* __restrict__ out, int N) {
    __shared__ long long smid[LDS_CAP];   // 32 KB
    int k = blockIdx.x;
    int t = threadIdx.x;
    int lane = t & 63;
    int wid = t >> 6;

    int beg = offs[k * NPART];
    int end = offs[k * NPART + NPART];
    int cnt = end - beg;
    int lcnt = cnt < LDS_CAP ? cnt : LDS_CAP;
    for (int i = t; i < lcnt; i += 256) smid[i] = mid[beg + i];
    __syncthreads();

    float4 acc[8];
#pragma unroll
    for (int j = 0; j < 8; ++j) acc[j] = make_float4(0.f, 0.f, 0.f, 0.f);

    for (int i = 0; i < cnt; ++i) {
        long long e = (i < LDS_CAP) ? smid[i] : mid[beg + i];
        unsigned lo = (unsigned)e;
        int dlo = (lo >> 20) & 31;
        if ((dlo & 3) != wid) continue;           // wave-uniform skip
        int src = lo & 0xFFFFF;
        float val = __int_as_float((int)(e >> 32));
        int j = dlo >> 2;
        if (USE_F16) {
            float2 raw = *((const float2*)(xh + (size_t)src * DN) + lane);
            __half2 h01 = *(__half2*)&raw.x;
            __half2 h23 = *(__half2*)&raw.y;
            float2 f01 = __half22float2(h01);
            float2 f23 = __half22float2(h23);
            acc[j].x = fmaf(val, f01.x, acc[j].x);
            acc[j].y = fmaf(val, f01.y, acc[j].y);
            acc[j].z = fmaf(val, f23.x, acc[j].z);
            acc[j].w = fmaf(val, f23.y, acc[j].w);
        } else {
            float4 r = *((const float4*)(xf + (size_t)src * DN) + lane);
            acc[j].x = fmaf(val, r.x, acc[j].x);
            acc[j].y = fmaf(val, r.y, acc[j].y);
            acc[j].z = fmaf(val, r.z, acc[j].z);
            acc[j].w = fmaf(val, r.w, acc[j].w);
        }
    }

#pragma unroll
    for (int j = 0; j < 8; ++j) {
        int node = k * BKT_NODES + j * 4 + wid;
        if (node < N) ((float4*)(out + (size_t)node * DN))[lane] = acc[j];
    }
}

// ---- MFMA split-bf16 GEMM: out = [agg|x] @ Wcat + bias -----------------

__device__ __forceinline__ void cvt8(const float4 a, const float4 b, u16x8& h, u16x8& lo) {
    float f[8] = {a.x, a.y, a.z, a.w, b.x, b.y, b.z, b.w};
#pragma unroll
    for (int j = 0; j < 8; ++j) {
        unsigned short hb = f2b(f[j]);
        h[j] = hb;
        lo[j] = f2b(f[j] - b2f(hb));
    }
}

__global__ __launch_bounds__(512) void k_gemm(const float* __restrict__ x,
                                              const unsigned short* __restrict__ wth,
                                              const unsigned short* __restrict__ wtl,
                                              const float* __restrict__ bias,
                                              float* __restrict__ out, int N) {
    __shared__ unsigned short Ah[GBM * GBK];   // 16 KB, XOR-swizzled rows of 128B
    __shared__ unsigned short Al[GBM * GBK];   // 16 KB

    int t = threadIdx.x;
    int l = t & 63;
    int wid = t >> 6;
    int wr = wid >> 2;
    int wc = wid & 3;
    int r0 = blockIdx.x * GBM;
    int lr = l & 15;
    int lg = l >> 4;

    f32x4 acc[4][4];
#pragma unroll
    for (int m = 0; m < 4; ++m)
#pragma unroll
        for (int n = 0; n < 4; ++n) acc[m][n] = (f32x4)(0.f);

    int srow = t >> 2;
    int sseg = t & 3;

#pragma unroll 1
    for (int c = 0; c < 8; ++c) {
        int k0 = c * GBK;
        const float* src = (k0 < 256) ? out : x;
        int kc = k0 & 255;
        __syncthreads();
        {
            int grow = r0 + srow;
            if (grow >= N) grow = N - 1;
            const float4* p = (const float4*)(src + (size_t)grow * DN + kc + sseg * 16);
            float4 v0 = p[0], v1 = p[1], v2 = p[2], v3 = p[3];
            u16x8 h0, l0, h1, l1;
            cvt8(v0, v1, h0, l0);
            cvt8(v2, v3, h1, l1);
            int kg0 = sseg * 2, kg1 = sseg * 2 + 1;
            int rb = srow * 128;
            int sw = (srow & 7) << 4;
            *(u16x8*)((char*)Ah + rb + (((kg0 << 4)) ^ sw)) = h0;
            *(u16x8*)((char*)Al + rb + (((kg0 << 4)) ^ sw)) = l0;
            *(u16x8*)((char*)Ah + rb + (((kg1 << 4)) ^ sw)) = h1;
            *(u16x8*)((char*)Al + rb + (((kg1 << 4)) ^ sw)) = l1;
        }
        __syncthreads();
#pragma unroll
        for (int ks = 0; ks < 2; ++ks) {
            bf16x8 ah[4], al[4], bh[4], bl[4];
            int kg = ks * 4 + lg;
#pragma unroll
            for (int m = 0; m < 4; ++m) {
                int rl = wr * 64 + m * 16 + lr;
                int off = rl * 128 + (((kg << 4)) ^ ((rl & 7) << 4));
                ah[m] = *(const bf16x8*)((const char*)Ah + off);
                al[m] = *(const bf16x8*)((const char*)Al + off);
            }
#pragma unroll
            for (int n = 0; n < 4; ++n) {
                int col = wc * 64 + n * 16 + lr;
                size_t e = (size_t)col * KTOT + k0 + ks * 32 + lg * 8;
                bh[n] = *(const bf16x8*)(wth + e);
                bl[n] = *(const bf16x8*)(wtl + e);
            }
#pragma unroll
            for (int m = 0; m < 4; ++m)
#pragma unroll
                for (int n = 0; n < 4; ++n) {
                    acc[m][n] = __builtin_amdgcn_mfma_f32_16x16x32_bf16(ah[m], bh[n], acc[m][n], 0, 0, 0);
                    acc[m][n] = __builtin_amdgcn_mfma_f32_16x16x32_bf16(ah[m], bl[n], acc[m][n], 0, 0, 0);
                    acc[m][n] = __builtin_amdgcn_mfma_f32_16x16x32_bf16(al[m], bh[n], acc[m][n], 0, 0, 0);
                }
        }
    }

    float bv[4];
#pragma unroll
    for (int n = 0; n < 4; ++n) bv[n] = bias[wc * 64 + n * 16 + lr];

#pragma unroll
    for (int m = 0; m < 4; ++m) {
#pragma unroll
        for (int j = 0; j < 4; ++j) {
            int grow = r0 + wr * 64 + m * 16 + lg * 4 + j;
            if (grow < N) {
                float* orow = out + (size_t)grow * DN + wc * 64;
#pragma unroll
                for (int n = 0; n < 4; ++n) orow[n * 16 + lr] = acc[m][n][j] + bv[n];
            }
        }
    }
}

// ---- launch ------------------------------------------------------------

extern "C" void kernel_launch(void* const* d_in, const int* in_sizes, int n_in,
                              void* d_out, int out_size, void* d_ws, size_t ws_size,
                              hipStream_t stream) {
    const float* x    = (const float*)d_in[0];
    const int*   esrc = (const int*)d_in[1];
    const int*   edst = (const int*)d_in[2];
    const float* vals = (const float*)d_in[3];
    const float* wn   = (const float*)d_in[4];
    const float* wo   = (const float*)d_in[5];
    const float* bias = (const float*)d_in[6];
    float* out = (float*)d_out;

    int N = in_sizes[0] / DN;
    int E = in_sizes[1];

    int NBKT = (N + BKT_NODES - 1) / BKT_NODES;   // 3125
    int L = NBKT * NPART;                          // 25000

    char* ws = (char*)d_ws;
    size_t off = 0;
    auto alloc = [&](size_t bytes) { void* p = ws + off; off = (off + bytes + 255) & ~(size_t)255; return p; };

    int* hist     = (int*)alloc((size_t)L * 4);
    int* offs     = (int*)alloc((size_t)(L + 1) * 4);
    int* cursor   = (int*)alloc((size_t)L * 4);
    int* bsum     = (int*)alloc(512);
    int* boffs    = (int*)alloc(512);
    long long* mid = (long long*)alloc((size_t)E * 8);
    unsigned short* wth = (unsigned short*)alloc((size_t)DN * KTOT * 2);
    unsigned short* wtl = (unsigned short*)alloc((size_t)DN * KTOT * 2);
    size_t xh_bytes = (size_t)N * DN * 2;
    bool use_f16 = (off + xh_bytes) <= ws_size;
    __half* xh = use_f16 ? (__half*)alloc(xh_bytes) : nullptr;

    int NB = (L + 1023) / 1024;                    // 25
    int EB = (E + 255) / 256;                      // 12500

    hipMemsetAsync(hist, 0, (size_t)L * 4, stream);
    k_cvt_w<<<(KTOT * DN) / 256, 256, 0, stream>>>(wn, wo, wth, wtl);
    if (use_f16) {
        int total8 = N * DN / 8;
        k_cvt_x<<<(total8 + 255) / 256, 256, 0, stream>>>(x, xh, total8);
    }
    k_bhist<<<EB, 256, 0, stream>>>(edst, hist, E);
    k_block_sums<<<NB, 256, 0, stream>>>(hist, bsum, L);
    k_scan_bsums<<<1, 128, 0, stream>>>(bsum, boffs, NB);
    k_scan_final<<<NB, 256, 0, stream>>>(hist, boffs, offs, cursor, L, E);
    k_bscatter<<<EB, 256, 0, stream>>>(esrc, edst, vals, cursor, mid, E);
    if (use_f16)
        k_agg_bkt<1><<<NBKT, 256, 0, stream>>>(xh, x, offs, mid, out, N);
    else
        k_agg_bkt<0><<<NBKT, 256, 0, stream>>>(xh, x, offs, mid, out, N);
    k_gemm<<<(N + GBM - 1) / GBM, 512, 0, stream>>>(x, wth, wtl, bias, out, N);
}

// Round 8
// 966.813 us; speedup vs baseline: 2.0868x; 2.0868x over previous
//
#include <hip/hip_runtime.h>
#include <hip/hip_fp16.h>

#define DN 256
#define KTOT 512
#define GBM 128
#define GBK 64
#define BKT_NODES 32
#define NPART 8
#define LDS_CAP 2048

typedef __attribute__((ext_vector_type(8))) short bf16x8;
typedef __attribute__((ext_vector_type(8))) unsigned short u16x8;
typedef __attribute__((ext_vector_type(4))) float f32x4;

__device__ __forceinline__ unsigned short f2b(float f) {
    unsigned u = __float_as_uint(f);
    u += 0x7FFF + ((u >> 16) & 1);   // round-to-nearest-even
    return (unsigned short)(u >> 16);
}
__device__ __forceinline__ float b2f(unsigned short b) {
    return __uint_as_float(((unsigned)b) << 16);
}

// ---- bucket binning ----------------------------------------------------
// key = (dst >> 5) * 8 + (blockIdx.x & 7). Partition term is a perf-only
// XCD-locality proxy; counts are exact because both passes use the same
// blockIdx-derived key.

__global__ void k_bhist(const int* __restrict__ edst, int* __restrict__ hist, int E) {
    int e = blockIdx.x * 256 + threadIdx.x;
    if (e < E) atomicAdd(&hist[(edst[e] >> 5) * NPART + (blockIdx.x & 7)], 1);
}

__global__ void k_bscatter(const int* __restrict__ esrc, const int* __restrict__ edst,
                           const float* __restrict__ vals, int* __restrict__ cursor,
                           long long* __restrict__ mid, int E) {
    int e = blockIdx.x * 256 + threadIdx.x;
    if (e < E) {
        int d = edst[e];
        int pos = atomicAdd(&cursor[(d >> 5) * NPART + (blockIdx.x & 7)], 1);
        unsigned lo = (unsigned)esrc[e] | ((unsigned)(d & 31) << 20);  // src<2^20
        mid[pos] = (long long)lo | ((long long)(unsigned)__float_as_int(vals[e]) << 32);
    }
}

// ---- generic hierarchical exclusive scan (L <= 128*1024) ---------------

__global__ void k_block_sums(const int* __restrict__ v, int* __restrict__ bsum, int L) {
    __shared__ int s[256];
    int t = threadIdx.x;
    int base = blockIdx.x * 1024 + t * 4;
    int sum = 0;
#pragma unroll
    for (int j = 0; j < 4; ++j) {
        int i = base + j;
        if (i < L) sum += v[i];
    }
    s[t] = sum;
    __syncthreads();
    for (int off = 128; off > 0; off >>= 1) {
        if (t < off) s[t] += s[t + off];
        __syncthreads();
    }
    if (t == 0) bsum[blockIdx.x] = s[0];
}

__global__ void k_scan_bsums(const int* __restrict__ bsum, int* __restrict__ boffs, int NB) {
    __shared__ int s[128];
    int t = threadIdx.x;
    int v = (t < NB) ? bsum[t] : 0;
    s[t] = v;
    __syncthreads();
    for (int off = 1; off < 128; off <<= 1) {
        int u = (t >= off) ? s[t - off] : 0;
        __syncthreads();
        s[t] += u;
        __syncthreads();
    }
    if (t < NB) boffs[t] = s[t] - v;
}

__global__ void k_scan_final(const int* __restrict__ v, const int* __restrict__ boffs,
                             int* __restrict__ offs, int* __restrict__ cursor,
                             int L, int E) {
    __shared__ int s[256];
    int t = threadIdx.x;
    int base = blockIdx.x * 1024 + t * 4;
    int d[4];
    int sum = 0;
#pragma unroll
    for (int j = 0; j < 4; ++j) {
        int i = base + j;
        d[j] = (i < L) ? v[i] : 0;
        sum += d[j];
    }
    s[t] = sum;
    __syncthreads();
    for (int off = 1; off < 256; off <<= 1) {
        int u = (t >= off) ? s[t - off] : 0;
        __syncthreads();
        s[t] += u;
        __syncthreads();
    }
    int p = boffs[blockIdx.x] + s[t] - sum;
#pragma unroll
    for (int j = 0; j < 4; ++j) {
        int i = base + j;
        if (i < L) {
            offs[i]   = p;
            cursor[i] = p;
            p += d[j];
        }
    }
    if (blockIdx.x == 0 && t == 0) offs[L] = E;
}

// ---- conversions -------------------------------------------------------

__global__ void k_cvt_x(const float* __restrict__ x, __half* __restrict__ xh, int total8) {
    int t = blockIdx.x * blockDim.x + threadIdx.x;
    if (t >= total8) return;
    const float4* p = (const float4*)(x + (size_t)t * 8);
    float4 a = p[0], b = p[1];
    __half h[8];
    h[0] = __float2half(a.x); h[1] = __float2half(a.y);
    h[2] = __float2half(a.z); h[3] = __float2half(a.w);
    h[4] = __float2half(b.x); h[5] = __float2half(b.y);
    h[6] = __float2half(b.z); h[7] = __float2half(b.w);
    *(u16x8*)(xh + (size_t)t * 8) = *(const u16x8*)h;
}

// Wcat[512][256] -> transposed split bf16: wt_hi/wt_lo layout [n][k]
__global__ void k_cvt_w(const float* __restrict__ wn, const float* __restrict__ wo,
                        unsigned short* __restrict__ wth, unsigned short* __restrict__ wtl) {
    int t = blockIdx.x * blockDim.x + threadIdx.x;  // t = k*256 + n
    int k = t >> 8;
    int n = t & 255;
    float v = (k < 256) ? wn[k * 256 + n] : wo[(k - 256) * 256 + n];
    unsigned short h = f2b(v);
    unsigned short l = f2b(v - b2f(h));
    wth[(size_t)n * KTOT + k] = h;
    wtl[(size_t)n * KTOT + k] = l;
}

// ---- sorted bucket aggregation: agg = A @ x into out -------------------
// one block per 32-node bucket: in-LDS counting sort by node, then each
// wave processes its 8 nodes sequentially with SCALAR accumulators (no
// runtime-indexed arrays -> no scratch).

template<int USE_F16>
__global__ __launch_bounds__(256) void k_agg_srt(const __half* __restrict__ xh,
                                                 const float* __restrict__ xf,
                                                 const int* __restrict__ offs,
                                                 const long long* __restrict__ mid,
                                                 float* __restrict__ out, int N) {
    __shared__ long long ssort[LDS_CAP];      // 16 KB
    __shared__ int cnt32[BKT_NODES];
    __shared__ int start[BKT_NODES + 1];
    __shared__ int cur[BKT_NODES];

    int k = blockIdx.x;
    int t = threadIdx.x;
    int lane = t & 63;
    int wid = t >> 6;

    int beg = offs[k * NPART];
    int end = offs[k * NPART + NPART];
    int cnt = end - beg;
    int lcnt = cnt < LDS_CAP ? cnt : LDS_CAP;

    if (t < BKT_NODES) cnt32[t] = 0;
    __syncthreads();

    // phase 1: load up to 8 edges/thread (static indices), count per node
    long long ed[8];
#pragma unroll
    for (int r = 0; r < 8; ++r) {
        int i = t + r * 256;
        if (i < lcnt) {
            long long e = mid[beg + i];
            ed[r] = e;
            atomicAdd(&cnt32[((unsigned)e >> 20) & 31], 1);
        } else {
            ed[r] = 0;
        }
    }
    __syncthreads();
    if (t == 0) {
        int s = 0;
#pragma unroll
        for (int v = 0; v < BKT_NODES; ++v) { start[v] = s; cur[v] = s; s += cnt32[v]; }
        start[BKT_NODES] = s;
    }
    __syncthreads();
    // phase 2: scatter into sorted order
#pragma unroll
    for (int r = 0; r < 8; ++r) {
        int i = t + r * 256;
        if (i < lcnt) {
            int v = ((unsigned)ed[r] >> 20) & 31;
            int pos = atomicAdd(&cur[v], 1);
            ssort[pos] = ed[r];
        }
    }
    __syncthreads();

    // phase 3: wave wid owns nodes v with (v & 3) == wid; scalar acc
    for (int j = 0; j < 8; ++j) {
        int v = j * 4 + wid;
        int s0 = start[v], s1 = start[v + 1];
        float ax = 0.f, ay = 0.f, az = 0.f, aw = 0.f;
        for (int i = s0; i < s1; ++i) {
            long long e = ssort[i];
            unsigned lo = (unsigned)e;
            int src = lo & 0xFFFFF;
            float val = __int_as_float((int)(e >> 32));
            if (USE_F16) {
                float2 raw = *((const float2*)(xh + (size_t)src * DN) + lane);
                __half2 h01 = *(__half2*)&raw.x;
                __half2 h23 = *(__half2*)&raw.y;
                float2 f01 = __half22float2(h01);
                float2 f23 = __half22float2(h23);
                ax = fmaf(val, f01.x, ax); ay = fmaf(val, f01.y, ay);
                az = fmaf(val, f23.x, az); aw = fmaf(val, f23.y, aw);
            } else {
                float4 r = *((const float4*)(xf + (size_t)src * DN) + lane);
                ax = fmaf(val, r.x, ax); ay = fmaf(val, r.y, ay);
                az = fmaf(val, r.z, az); aw = fmaf(val, r.w, aw);
            }
        }
        int node = k * BKT_NODES + v;
        if (node < N)
            ((float4*)(out + (size_t)node * DN))[lane] = make_float4(ax, ay, az, aw);
    }

    // overflow fallback (cnt > LDS_CAP): statistically never taken; each
    // wave atomically adds into rows it owns (already written above).
    if (cnt > LDS_CAP) {
        for (int i = lcnt; i < cnt; ++i) {
            long long e = mid[beg + i];
            unsigned lo = (unsigned)e;
            int dlo = (lo >> 20) & 31;
            if ((dlo & 3) != wid) continue;
            int src = lo & 0xFFFFF;
            float val = __int_as_float((int)(e >> 32));
            float vx, vy, vz, vw;
            if (USE_F16) {
                float2 raw = *((const float2*)(xh + (size_t)src * DN) + lane);
                __half2 h01 = *(__half2*)&raw.x;
                __half2 h23 = *(__half2*)&raw.y;
                float2 f01 = __half22float2(h01);
                float2 f23 = __half22float2(h23);
                vx = f01.x; vy = f01.y; vz = f23.x; vw = f23.y;
            } else {
                float4 r = *((const float4*)(xf + (size_t)src * DN) + lane);
                vx = r.x; vy = r.y; vz = r.z; vw = r.w;
            }
            int node = k * BKT_NODES + dlo;
            if (node < N) {
                float* orow = out + (size_t)node * DN + lane * 4;
                atomicAdd(orow + 0, val * vx);
                atomicAdd(orow + 1, val * vy);
                atomicAdd(orow + 2, val * vz);
                atomicAdd(orow + 3, val * vw);
            }
        }
    }
}

// ---- MFMA split-bf16 GEMM: out = [agg|x] @ Wcat + bias -----------------

__device__ __forceinline__ void cvt8(const float4 a, const float4 b, u16x8& h, u16x8& lo) {
    float f[8] = {a.x, a.y, a.z, a.w, b.x, b.y, b.z, b.w};
#pragma unroll
    for (int j = 0; j < 8; ++j) {
        unsigned short hb = f2b(f[j]);
        h[j] = hb;
        lo[j] = f2b(f[j] - b2f(hb));
    }
}

__global__ __launch_bounds__(512) void k_gemm(const float* __restrict__ x,
                                              const unsigned short* __restrict__ wth,
                                              const unsigned short* __restrict__ wtl,
                                              const float* __restrict__ bias,
                                              float* __restrict__ out, int N) {
    __shared__ unsigned short Ah[GBM * GBK];   // 16 KB, XOR-swizzled rows of 128B
    __shared__ unsigned short Al[GBM * GBK];   // 16 KB

    int t = threadIdx.x;
    int l = t & 63;
    int wid = t >> 6;
    int wr = wid >> 2;
    int wc = wid & 3;
    int r0 = blockIdx.x * GBM;
    int lr = l & 15;
    int lg = l >> 4;

    f32x4 acc[4][4];
#pragma unroll
    for (int m = 0; m < 4; ++m)
#pragma unroll
        for (int n = 0; n < 4; ++n) acc[m][n] = (f32x4)(0.f);

    int srow = t >> 2;
    int sseg = t & 3;

#pragma unroll 1
    for (int c = 0; c < 8; ++c) {
        int k0 = c * GBK;
        const float* src = (k0 < 256) ? out : x;
        int kc = k0 & 255;
        __syncthreads();
        {
            int grow = r0 + srow;
            if (grow >= N) grow = N - 1;
            const float4* p = (const float4*)(src + (size_t)grow * DN + kc + sseg * 16);
            float4 v0 = p[0], v1 = p[1], v2 = p[2], v3 = p[3];
            u16x8 h0, l0, h1, l1;
            cvt8(v0, v1, h0, l0);
            cvt8(v2, v3, h1, l1);
            int kg0 = sseg * 2, kg1 = sseg * 2 + 1;
            int rb = srow * 128;
            int sw = (srow & 7) << 4;
            *(u16x8*)((char*)Ah + rb + (((kg0 << 4)) ^ sw)) = h0;
            *(u16x8*)((char*)Al + rb + (((kg0 << 4)) ^ sw)) = l0;
            *(u16x8*)((char*)Ah + rb + (((kg1 << 4)) ^ sw)) = h1;
            *(u16x8*)((char*)Al + rb + (((kg1 << 4)) ^ sw)) = l1;
        }
        __syncthreads();
#pragma unroll
        for (int ks = 0; ks < 2; ++ks) {
            bf16x8 ah[4], al[4], bh[4], bl[4];
            int kg = ks * 4 + lg;
#pragma unroll
            for (int m = 0; m < 4; ++m) {
                int rl = wr * 64 + m * 16 + lr;
                int off = rl * 128 + (((kg << 4)) ^ ((rl & 7) << 4));
                ah[m] = *(const bf16x8*)((const char*)Ah + off);
                al[m] = *(const bf16x8*)((const char*)Al + off);
            }
#pragma unroll
            for (int n = 0; n < 4; ++n) {
                int col = wc * 64 + n * 16 + lr;
                size_t e = (size_t)col * KTOT + k0 + ks * 32 + lg * 8;
                bh[n] = *(const bf16x8*)(wth + e);
                bl[n] = *(const bf16x8*)(wtl + e);
            }
#pragma unroll
            for (int m = 0; m < 4; ++m)
#pragma unroll
                for (int n = 0; n < 4; ++n) {
                    acc[m][n] = __builtin_amdgcn_mfma_f32_16x16x32_bf16(ah[m], bh[n], acc[m][n], 0, 0, 0);
                    acc[m][n] = __builtin_amdgcn_mfma_f32_16x16x32_bf16(ah[m], bl[n], acc[m][n], 0, 0, 0);
                    acc[m][n] = __builtin_amdgcn_mfma_f32_16x16x32_bf16(al[m], bh[n], acc[m][n], 0, 0, 0);
                }
        }
    }

    float bv[4];
#pragma unroll
    for (int n = 0; n < 4; ++n) bv[n] = bias[wc * 64 + n * 16 + lr];

#pragma unroll
    for (int m = 0; m < 4; ++m) {
#pragma unroll
        for (int j = 0; j < 4; ++j) {
            int grow = r0 + wr * 64 + m * 16 + lg * 4 + j;
            if (grow < N) {
                float* orow = out + (size_t)grow * DN + wc * 64;
#pragma unroll
                for (int n = 0; n < 4; ++n) orow[n * 16 + lr] = acc[m][n][j] + bv[n];
            }
        }
    }
}

// ---- launch ------------------------------------------------------------

extern "C" void kernel_launch(void* const* d_in, const int* in_sizes, int n_in,
                              void* d_out, int out_size, void* d_ws, size_t ws_size,
                              hipStream_t stream) {
    const float* x    = (const float*)d_in[0];
    const int*   esrc = (const int*)d_in[1];
    const int*   edst = (const int*)d_in[2];
    const float* vals = (const float*)d_in[3];
    const float* wn   = (const float*)d_in[4];
    const float* wo   = (const float*)d_in[5];
    const float* bias = (const float*)d_in[6];
    float* out = (float*)d_out;

    int N = in_sizes[0] / DN;
    int E = in_sizes[1];

    int NBKT = (N + BKT_NODES - 1) / BKT_NODES;   // 3125
    int L = NBKT * NPART;                          // 25000

    char* ws = (char*)d_ws;
    size_t off = 0;
    auto alloc = [&](size_t bytes) { void* p = ws + off; off = (off + bytes + 255) & ~(size_t)255; return p; };

    int* hist     = (int*)alloc((size_t)L * 4);
    int* offs     = (int*)alloc((size_t)(L + 1) * 4);
    int* cursor   = (int*)alloc((size_t)L * 4);
    int* bsum     = (int*)alloc(512);
    int* boffs    = (int*)alloc(512);
    long long* mid = (long long*)alloc((size_t)E * 8);
    unsigned short* wth = (unsigned short*)alloc((size_t)DN * KTOT * 2);
    unsigned short* wtl = (unsigned short*)alloc((size_t)DN * KTOT * 2);
    size_t xh_bytes = (size_t)N * DN * 2;
    bool use_f16 = (off + xh_bytes) <= ws_size;
    __half* xh = use_f16 ? (__half*)alloc(xh_bytes) : nullptr;

    int NB = (L + 1023) / 1024;                    // 25
    int EB = (E + 255) / 256;                      // 12500

    hipMemsetAsync(hist, 0, (size_t)L * 4, stream);
    k_cvt_w<<<(KTOT * DN) / 256, 256, 0, stream>>>(wn, wo, wth, wtl);
    if (use_f16) {
        int total8 = N * DN / 8;
        k_cvt_x<<<(total8 + 255) / 256, 256, 0, stream>>>(x, xh, total8);
    }
    k_bhist<<<EB, 256, 0, stream>>>(edst, hist, E);
    k_block_sums<<<NB, 256, 0, stream>>>(hist, bsum, L);
    k_scan_bsums<<<1, 128, 0, stream>>>(bsum, boffs, NB);
    k_scan_final<<<NB, 256, 0, stream>>>(hist, boffs, offs, cursor, L, E);
    k_bscatter<<<EB, 256, 0, stream>>>(esrc, edst, vals, cursor, mid, E);
    if (use_f16)
        k_agg_srt<1><<<NBKT, 256, 0, stream>>>(xh, x, offs, mid, out, N);
    else
        k_agg_srt<0><<<NBKT, 256, 0, stream>>>(xh, x, offs, mid, out, N);
    k_gemm<<<(N + GBM - 1) / GBM, 512, 0, stream>>>(x, wth, wtl, bias, out, N);
}